// Round 2
// baseline (154.268 us; speedup 1.0000x reference)
//
#include <hip/hip_runtime.h>
#include <hip/hip_bf16.h>

#define BIG 3.4e38f

// ---------- top-5 helpers ----------

// Merge two ascending sorted 5-lists, keep the 5 smallest in a[].
__device__ __forceinline__ void merge5(float a[5], const float* b) {
    float r[5];
#pragma unroll
    for (int k = 0; k < 5; ++k) {
        float best = BIG;
#pragma unroll
        for (int i = 0; i <= k + 1; ++i) {
            const int j = k + 1 - i;
            float va = (i == 0) ? -BIG : a[i - 1];
            float vb = (j == 0) ? -BIG : b[j - 1];
            best = fminf(best, fmaxf(va, vb));
        }
        r[k] = best;
    }
#pragma unroll
    for (int k = 0; k < 5; ++k) a[k] = r[k];
}

__device__ __forceinline__ void top5_insert(float m[5], float d) {
    if (d < m[4]) {
        m[4] = d;
#pragma unroll
        for (int k = 4; k > 0; --k) {
            float lo = fminf(m[k - 1], m[k]);
            float hi = fmaxf(m[k - 1], m[k]);
            m[k - 1] = lo;
            m[k] = hi;
        }
    }
}

__device__ __forceinline__ void wave_merge_top5(float m[5]) {
#pragma unroll
    for (int off = 1; off < 64; off <<= 1) {
        float o[5];
#pragma unroll
        for (int k = 0; k < 5; ++k) o[k] = __shfl_xor(m[k], off, 64);
        merge5(m, o);
    }
}

__device__ __forceinline__ bool block_merge_top5(float m[5], float (*s_top)[5],
                                                 float r[5]) {
    const int wid = threadIdx.x >> 6;
    if ((threadIdx.x & 63) == 0) {
#pragma unroll
        for (int k = 0; k < 5; ++k) s_top[wid][k] = m[k];
    }
    __syncthreads();
    if (threadIdx.x == 0) {
#pragma unroll
        for (int k = 0; k < 5; ++k) r[k] = s_top[0][k];
        merge5(r, s_top[1]);
        merge5(r, s_top[2]);
        merge5(r, s_top[3]);
        return true;
    }
    return false;
}

// ---------- K1 (single fused pass, no dist planes) ----------
// Blocks [0,506): scale-0. One (h-row, 128-col half) tile per block.
//   256 threads = 4 channel-quarters (wave q owns channels 16q..16q+15)
//   x 64 pos-threads x 2 positions. Register partials acc[10][2], one
//   aligned float4 src load per (c,i). LDS exchange sums the 4 quarters
//   (stride 21 -> <=2-way banks, free), then each wave does block top-5
//   for targets t = q, q+4, q+8 and writes 5 floats -> p2a. No dist0,
//   no stage-2 kernel.
// Blocks [506,570): scale-1 (C=128, ps=1) full distance + block top-5 -> p2b.
__global__ __launch_bounds__(256) void dist_all_kernel(
    const float* __restrict__ src0, const float* __restrict__ tgt0,
    const int* __restrict__ pos0, const float* __restrict__ src1,
    const float* __restrict__ tgt1, const int* __restrict__ pos1,
    float* __restrict__ p2a, float* __restrict__ p2b) {
    __shared__ float tl[10 * 64 * 12];  // 30720 B; scale-1 uses first 640
    __shared__ float sex[256 * 21];     // 21504 B quarter-partial exchange
    __shared__ float s_top[4][5];

    const int b = blockIdx.x;
    if (b < 506) {
        // ---- scale 0: C=64, H=W=256, ps=3 ----
        constexpr int W = 256, HW = 65536, T = 10;
        const int h = b >> 1;
        const int wbase = (b & 1) << 7;  // 0 or 128

        // Gather all 10 target patches, full C=64 (tiny, L2-resident).
        for (int idx = threadIdx.x; idx < T * 64 * 9; idx += 256) {
            int t = idx / 576;
            int rem = idx - t * 576;
            int c = rem / 9;
            int r2 = rem - c * 9;
            int i = r2 / 3, j = r2 - i * 3;
            tl[((t * 64 + c) * 3 + i) * 4 + j] =
                tgt0[(size_t)c * HW + (pos0[2 * t] + i) * W +
                     (pos0[2 * t + 1] + j)];
        }
        __syncthreads();

        const int p = threadIdx.x & 63;  // pos-thread
        const int q = threadIdx.x >> 6;  // channel quarter == wave id
        const int w0 = wbase + 2 * p;
        const int w0l = (w0 <= 252) ? w0 : 252;  // clamp: keep loads in-row

        float acc[T][2];
#pragma unroll
        for (int t = 0; t < T; ++t) acc[t][0] = acc[t][1] = 0.f;

        const float* sb = src0 + (size_t)(q * 16) * HW + h * W + w0l;
        for (int c = 0; c < 16; ++c) {
            const float* row = sb + (size_t)c * HW;
#pragma unroll
            for (int i = 0; i < 3; ++i) {
                const float4 a = *(const float4*)(row + i * W);
#pragma unroll
                for (int t = 0; t < T; ++t) {
                    const float4 tv = *(const float4*)&tl
                        [((t * 64 + q * 16 + c) * 3 + i) * 4];
                    acc[t][0] += fabsf(a.x - tv.x) + fabsf(a.y - tv.y) +
                                 fabsf(a.z - tv.z);
                    acc[t][1] += fabsf(a.y - tv.x) + fabsf(a.z - tv.y) +
                                 fabsf(a.w - tv.z);
                }
            }
        }

        // Exchange quarter-partials through LDS (stride 21: <=2-way banks).
        {
            float* se = &sex[threadIdx.x * 21];
#pragma unroll
            for (int t = 0; t < T; ++t) {
                se[2 * t] = acc[t][0];
                se[2 * t + 1] = acc[t][1];
            }
        }
        __syncthreads();

        // Wave q reduces targets q, q+4, q+8 over the block's 128 positions.
        for (int t = q; t < T; t += 4) {
            const int ke = 2 * t + (p & 1);
            const int pr = (p >> 1) * 21;
            float dlo = 0.f, dhi = 0.f;
#pragma unroll
            for (int qq = 0; qq < 4; ++qq) {
                dlo += sex[qq * 64 * 21 + pr + ke];
                dhi += sex[qq * 64 * 21 + 32 * 21 + pr + ke];
            }
            if (wbase + p >= 253) dlo = BIG;       // pos id p  -> w=wbase+p
            if (wbase + p + 64 >= 253) dhi = BIG;  // pos id p+64
            float m[5] = {dlo, BIG, BIG, BIG, BIG};
            top5_insert(m, dhi);
            wave_merge_top5(m);
            if (p == 0) {
                float* dst = p2a + (t * 506 + b) * 5;
#pragma unroll
                for (int k = 0; k < 5; ++k) dst[k] = m[k];
            }
        }
    } else {
        // ---- scale 1: C=128, H=W=128, ps=1 — full dist + block top-5 ----
        constexpr int W = 128, HW = 16384, T = 5, C = 128;
        const int bb = b - 506;
        for (int idx = threadIdx.x; idx < T * C; idx += 256) {
            int t = idx / C, cc = idx - t * C;
            tl[idx] =
                tgt1[(size_t)cc * HW + pos1[2 * t] * W + pos1[2 * t + 1]];
        }
        __syncthreads();

        const int w = threadIdx.x & 127;
        const int h = bb * 2 + (threadIdx.x >> 7);  // 0..127
        float acc[T] = {0.f, 0.f, 0.f, 0.f, 0.f};
        const float* sp = src1 + h * W + w;
        for (int cc = 0; cc < C; ++cc) {
            const float v = sp[(size_t)cc * HW];
#pragma unroll
            for (int t = 0; t < T; ++t) acc[t] += fabsf(v - tl[t * C + cc]);
        }
        const bool valid = (h < 127) && (w < 127);
#pragma unroll
        for (int t = 0; t < T; ++t) {
            float m[5] = {valid ? acc[t] : BIG, BIG, BIG, BIG, BIG};
            wave_merge_top5(m);
            float r[5];
            if (block_merge_top5(m, s_top, r)) {
                float* dst = p2b + (t * 64 + bb) * 5;
#pragma unroll
                for (int k = 0; k < 5; ++k) dst[k] = r[k];
            }
            __syncthreads();  // s_top reuse across targets
        }
    }
}

// ---------- K3: parallel-over-targets final merge + scalar write --------
// Output word: high16 = f32 bits, low16 = RNE bf16 bits (dtype-proof).
// Loads batched 4-wide per iteration so the merge loop pipelines.
__global__ __launch_bounds__(256) void final_merge_kernel(
    const float* __restrict__ p2a, int na,
    const float* __restrict__ p2b, int nb,
    unsigned int* __restrict__ out) {
    __shared__ float s_sum[15];
    const int lane = threadIdx.x & 63;
    const int wv = threadIdx.x >> 6;
#pragma unroll
    for (int rt = 0; rt < 4; ++rt) {
        const int t = wv * 4 + rt;
        if (t < 15) {
            const float* base = (t < 10) ? p2a + t * na : p2b + (t - 10) * nb;
            const int n = (t < 10) ? na : nb;
            const float scale =
                (t < 10) ? 1.f / (576.f * 5.f) : 1.f / (128.f * 5.f);
            float m[5] = {BIG, BIG, BIG, BIG, BIG};
            for (int b0 = 0; b0 < n; b0 += 256) {
                float v[4];
#pragma unroll
                for (int j = 0; j < 4; ++j) {
                    const int idx = b0 + j * 64 + lane;
                    v[j] = (idx < n) ? base[idx] : BIG;
                }
#pragma unroll
                for (int j = 0; j < 4; ++j) top5_insert(m, v[j]);
            }
            wave_merge_top5(m);
            if (lane == 0)
                s_sum[t] = (m[0] + m[1] + m[2] + m[3] + m[4]) * scale;
        }
    }
    __syncthreads();
    if (threadIdx.x == 0) {
        float total = 0.f;
#pragma unroll
        for (int t = 0; t < 15; ++t) total += s_sum[t];
        union { float f; unsigned int i; } uf;
        uf.f = total * 0.1f;
        unsigned int bf = (uf.i + 0x7FFFu + ((uf.i >> 16) & 1u)) >> 16;
        out[0] = (uf.i & 0xFFFF0000u) | (bf & 0xFFFFu);
    }
}

// ---------- fallback (round-2 proven path, tiny ws) ----------
template <int C, int H, int PS, int WM>
__global__ __launch_bounds__(256) void dist_top5_kernel(
    const float* __restrict__ src, const float* __restrict__ tgt,
    const int* __restrict__ pos, float* __restrict__ part) {
    constexpr int W = H;
    constexpr int K = C * PS * PS;
    constexpr int P = WM * WM;
    __shared__ float tlv[K];
    __shared__ float s_top[4][5];
    const int t = blockIdx.y;
    const int th = pos[2 * t], tw = pos[2 * t + 1];
    for (int idx = threadIdx.x; idx < K; idx += 256) {
        int c = idx / (PS * PS);
        int rem = idx - c * PS * PS;
        int i = rem / PS, j = rem - i * PS;
        tlv[idx] = tgt[(c * H + th + i) * W + tw + j];
    }
    __syncthreads();
    const int p = blockIdx.x * 256 + threadIdx.x;
    float d = BIG;
    if (p < P) {
        const int h = p / WM, w = p - h * WM;
        float acc = 0.f;
        for (int c = 0; c < C; ++c)
#pragma unroll
            for (int i = 0; i < PS; ++i) {
                const float* r = src + (c * H + h + i) * W + w;
                const float* tr = &tlv[(c * PS + i) * PS];
#pragma unroll
                for (int j = 0; j < PS; ++j) acc += fabsf(r[j] - tr[j]);
            }
        d = acc;
    }
    float m[5] = {d, BIG, BIG, BIG, BIG};
    wave_merge_top5(m);
    float r[5];
    if (block_merge_top5(m, s_top, r)) {
        float* dst = part + (t * gridDim.x + blockIdx.x) * 5;
#pragma unroll
        for (int k = 0; k < 5; ++k) dst[k] = r[k];
    }
}

extern "C" void kernel_launch(void* const* d_in, const int* in_sizes, int n_in,
                              void* d_out, int out_size, void* d_ws, size_t ws_size,
                              hipStream_t stream) {
    const float* src0 = (const float*)d_in[0];  // [1,64,256,256] f32
    const float* tgt0 = (const float*)d_in[1];
    const float* src1 = (const float*)d_in[2];  // [1,128,128,128] f32
    const float* tgt1 = (const float*)d_in[3];
    const int* pos0 = (const int*)d_in[4];      // [10,2]
    const int* pos1 = (const int*)d_in[5];      // [5,2]
    unsigned int* out = (unsigned int*)d_out;

    constexpr size_t NP2A = 10 * 506 * 5;  // 25300
    constexpr size_t NP2B = 5 * 64 * 5;    // 1600
    const size_t need = (NP2A + NP2B) * 4;

    if (ws_size >= need) {
        float* p2a = (float*)d_ws;
        float* p2b = p2a + NP2A;

        // K1: scale-0 fused dist+top5 (506 blocks) + scale-1 (64 blocks).
        dist_all_kernel<<<dim3(570), 256, 0, stream>>>(
            src0, tgt0, pos0, src1, tgt1, pos1, p2a, p2b);
        // K3: final merge (10 x 2530 values + 5 x 320 values).
        final_merge_kernel<<<dim3(1), 256, 0, stream>>>(
            p2a, 506 * 5, p2b, 320, out);
    } else {
        // Fallback: round-2 proven path (~57KB of ws).
        float* part0 = (float*)d_ws;
        float* part1 = part0 + 10 * 251 * 5;
        dist_top5_kernel<64, 256, 3, 253>
            <<<dim3(251, 10), 256, 0, stream>>>(src0, tgt0, pos0, part0);
        dist_top5_kernel<128, 128, 1, 127>
            <<<dim3(64, 5), 256, 0, stream>>>(src1, tgt1, pos1, part1);
        final_merge_kernel<<<dim3(1), 256, 0, stream>>>(part0, 1255, part1, 320, out);
    }
}